// Round 5
// baseline (28384.515 us; speedup 1.0000x reference)
//
#include <hip/hip_runtime.h>
#include <math.h>

typedef unsigned short u16;
typedef __attribute__((ext_vector_type(4))) float f4;

#define BB 32
#define TT 64
#define DD 512
#define G4_ 2048
#define NBLK 128
#define THR 256

__device__ __forceinline__ float sigf(float x) { return 1.0f / (1.0f + expf(-x)); }

// device-scope (cross-XCD coherent) scalar access for h-state exchange
__device__ __forceinline__ float aload(const float* p) {
    return __hip_atomic_load(const_cast<float*>(p), __ATOMIC_RELAXED,
                             __HIP_MEMORY_SCOPE_AGENT);
}
__device__ __forceinline__ void astore(float* p, float v) {
    __hip_atomic_store(p, v, __ATOMIC_RELAXED, __HIP_MEMORY_SCOPE_AGENT);
}

// ---------------------------------------------------------------------------
// mask dtype classifier: 0=u8(bool), 1=i32, 2=bf16, 3=f32. Deterministic.
// ---------------------------------------------------------------------------
__global__ void k_flag(const unsigned char* __restrict__ m, int* __restrict__ flag) {
    int tid = threadIdx.x;
    int badbyte = 0, nonz_off = 0, evenu16_nz = 0;
    for (int i = tid * 16; i < tid * 16 + 16; i++) {
        unsigned char c = m[i];
        if (c > 1) badbyte = 1;
        if ((i & 3) != 0 && c != 0) nonz_off = 1;
    }
    const u16* mu = (const u16*)m;
    for (int i = tid * 8; i < tid * 8 + 8; i++) {
        if ((i & 1) == 0 && mu[i] != 0) evenu16_nz = 1;
    }
    __shared__ int s_bad, s_noff, s_env;
    if (tid == 0) { s_bad = 0; s_noff = 0; s_env = 0; }
    __syncthreads();
    if (badbyte) atomicOr(&s_bad, 1);
    if (nonz_off) atomicOr(&s_noff, 1);
    if (evenu16_nz) atomicOr(&s_env, 1);
    __syncthreads();
    if (tid == 0) {
        int f;
        if (s_bad) f = s_env ? 2 : 3;
        else       f = s_noff ? 0 : 1;
        *flag = f;
    }
}

// ---------------------------------------------------------------------------
// init: copy initial h-states into both parity buffers; zero the barrier.
// ---------------------------------------------------------------------------
__global__ void __launch_bounds__(256) k_init2(const float* __restrict__ hid,
                                               float* __restrict__ h0s,
                                               float* __restrict__ h1s,
                                               int* __restrict__ bar) {
    int i = blockIdx.x * 256 + threadIdx.x;   // 0 .. 16383
    float v0 = hid[i], v1 = hid[16384 + i];
    h0s[i] = v0; h0s[16384 + i] = v0;
    h1s[i] = v1; h1s[16384 + i] = v1;
    if (i == 0) { bar[0] = 0; bar[1] = 0; }
}

// ---------------------------------------------------------------------------
// gih0[t][b][j] = b_ih0[j] + b_hh0[j] + sum_k embed[tok[b,t],k] * W_ih0[j,k]
// ---------------------------------------------------------------------------
__global__ void __launch_bounds__(256) k_gih0(const int* __restrict__ tokens,
                                              const float* __restrict__ embed,
                                              const float* __restrict__ Wih,
                                              const float* __restrict__ bih,
                                              const float* __restrict__ bhh,
                                              float* __restrict__ gih0) {
    const int tid = threadIdx.x;
    const int d0 = blockIdx.x * 8;
    const int t = blockIdx.y;
    const int b = tid & 31, dd = tid >> 5;
    const int d = d0 + dd;
    __shared__ float xs[32 * 257];
    __shared__ int toks[32];
    if (tid < 32) toks[tid] = tokens[tid * TT + t];
    float acc[4];
#pragma unroll
    for (int g = 0; g < 4; g++) { int j = g * 512 + d; acc[g] = bih[j] + bhh[j]; }
    __syncthreads();
    for (int c = 0; c < 2; c++) {
        for (int idx = tid; idx < 32 * 64; idx += 256) {
            int b2 = idx >> 6, k4 = idx & 63;
            f4 v = *(const f4*)&embed[(size_t)toks[b2] * 512 + c * 256 + k4 * 4];
            float* dst = &xs[b2 * 257 + k4 * 4];
            dst[0] = v[0]; dst[1] = v[1]; dst[2] = v[2]; dst[3] = v[3];
        }
        __syncthreads();
        for (int k8 = 0; k8 < 32; k8++) {
            float w[4][8];
#pragma unroll
            for (int g = 0; g < 4; g++) {
                const f4* wp = (const f4*)&Wih[(size_t)(g * 512 + d) * 512 + c * 256 + k8 * 8];
                f4 wa = wp[0], wb = wp[1];
#pragma unroll
                for (int kk = 0; kk < 4; kk++) { w[g][kk] = wa[kk]; w[g][4 + kk] = wb[kk]; }
            }
#pragma unroll
            for (int kk = 0; kk < 8; kk++) {
                float xv = xs[b * 257 + k8 * 8 + kk];
#pragma unroll
                for (int g = 0; g < 4; g++) acc[g] += xv * w[g][kk];
            }
        }
        __syncthreads();
    }
    float* grow = gih0 + ((size_t)(t * 32 + b)) * 2048;
#pragma unroll
    for (int g = 0; g < 4; g++) grow[g * 512 + d] = acc[g];
}

// ---------------------------------------------------------------------------
// Persistent recurrence (normal launch). 65 phases; phase k does
//   stepA(t=k) [k<64] and stepB(t=k-1) [k>=1], then a device barrier.
// ALL cross-block h-state exchange uses device-scope atomics (cross-XCD
// coherent); weights/gih0 stay plain (read-only, L2-cached).
// Block owns d-slice [d0, d0+4); col m = g*4+dd -> global row g*512+d0+dd.
// ---------------------------------------------------------------------------
__global__ void __launch_bounds__(256, 1) k_persist(
    const float* __restrict__ gih0,
    const float* __restrict__ Whh0,
    const float* __restrict__ Wih1,
    const float* __restrict__ Whh1,
    const float* __restrict__ bih1,
    const float* __restrict__ bhh1,
    const float* __restrict__ cells,
    float* __restrict__ h0s,    // [2][32][512]
    float* __restrict__ h20s,   // [2][32][512]
    float* __restrict__ h1s,    // [2][32][512]
    float* __restrict__ H2,     // [64][32][512]
    int* __restrict__ bar)      // [0]=counter [1]=generation
{
    const int blk = blockIdx.x, tid = threadIdx.x;
    const int d0 = blk * 4;
    const int b = tid & 31, u = tid >> 5;

    __shared__ float xs[32][257];
    __shared__ float gbuf[16][33];
    __shared__ float bb1[16];
    __shared__ float clds[2][128];

    if (tid < 16) {
        int j = (tid >> 2) * 512 + d0 + (tid & 3);
        bb1[tid] = bih1[j] + bhh1[j];
    }
    if (tid < 128) {
        int bb = tid & 31, dd = tid >> 5;
        clds[0][tid] = cells[bb * 512 + d0 + dd];
        clds[1][tid] = cells[16384 + bb * 512 + d0 + dd];
    }
    __syncthreads();

    const int m0 = u * 2, m1 = u * 2 + 1;
    const int j0 = (m0 >> 2) * 512 + d0 + (m0 & 3);
    const int j1 = (m1 >> 2) * 512 + d0 + (m1 & 3);
    const float* WA0 = Whh0 + (size_t)j0 * 512;
    const float* WA1 = Whh0 + (size_t)j1 * 512;
    const float* WI0 = Wih1 + (size_t)j0 * 512;
    const float* WI1 = Wih1 + (size_t)j1 * 512;
    const float* WH0 = Whh1 + (size_t)j0 * 512;
    const float* WH1 = Whh1 + (size_t)j1 * 512;

    for (int k = 0; k <= 64; k++) {
        const int r = k & 1, w = r ^ 1;

        if (k < 64) {                                   // ---- stepA (t = k)
            float a0 = gih0[(size_t)k * 65536 + b * 2048 + j0];
            float a1 = gih0[(size_t)k * 65536 + b * 2048 + j1];
            const float* h0r = h0s + r * 16384;
            for (int c = 0; c < 2; c++) {
                __syncthreads();
                for (int i = tid; i < 8192; i += THR) {
                    int b2 = i >> 8, kk = i & 255;
                    xs[b2][kk] = aload(&h0r[b2 * 512 + c * 256 + kk]);
                }
                __syncthreads();
                const float* w0p = WA0 + c * 256;
                const float* w1p = WA1 + c * 256;
                for (int k4 = 0; k4 < 64; k4++) {
                    f4 x = *(const f4*)&xs[b][k4 * 4];
                    f4 w0 = *(const f4*)&w0p[k4 * 4];
                    f4 w1 = *(const f4*)&w1p[k4 * 4];
                    a0 += x[0] * w0[0]; a0 += x[1] * w0[1]; a0 += x[2] * w0[2]; a0 += x[3] * w0[3];
                    a1 += x[0] * w1[0]; a1 += x[1] * w1[1]; a1 += x[2] * w1[2]; a1 += x[3] * w1[3];
                }
            }
            gbuf[m0][b] = a0; gbuf[m1][b] = a1;
            __syncthreads();
            if (tid < 128) {
                int bb = tid & 31, dd = tid >> 5;
                float gi = gbuf[0 + dd][bb], gf = gbuf[4 + dd][bb];
                float gg = gbuf[8 + dd][bb], go = gbuf[12 + dd][bb];
                float c2 = sigf(gf) * clds[0][tid] + sigf(gi) * tanhf(gg);
                float h2 = sigf(go) * tanhf(c2);
                astore(&h0s[w * 16384 + bb * 512 + d0 + dd], c2);   // faithful bug: carry = cell
                astore(&h20s[w * 16384 + bb * 512 + d0 + dd], h2);
            }
        }

        if (k >= 1) {                                   // ---- stepB (t = k-1)
            float a0 = bb1[m0], a1 = bb1[m1];
            const float* h2r = h20s + r * 16384;
            const float* h1r = h1s + r * 16384;
            for (int c = 0; c < 4; c++) {
                const float* srcb = (c < 2) ? h2r : h1r;
                const int off = (c & 1) * 256;
                const float* w0p = (c < 2) ? (WI0 + off) : (WH0 + off);
                const float* w1p = (c < 2) ? (WI1 + off) : (WH1 + off);
                __syncthreads();
                for (int i = tid; i < 8192; i += THR) {
                    int b2 = i >> 8, kk = i & 255;
                    xs[b2][kk] = aload(&srcb[b2 * 512 + off + kk]);
                }
                __syncthreads();
                for (int k4 = 0; k4 < 64; k4++) {
                    f4 x = *(const f4*)&xs[b][k4 * 4];
                    f4 w0 = *(const f4*)&w0p[k4 * 4];
                    f4 w1 = *(const f4*)&w1p[k4 * 4];
                    a0 += x[0] * w0[0]; a0 += x[1] * w0[1]; a0 += x[2] * w0[2]; a0 += x[3] * w0[3];
                    a1 += x[0] * w1[0]; a1 += x[1] * w1[1]; a1 += x[2] * w1[2]; a1 += x[3] * w1[3];
                }
            }
            gbuf[m0][b] = a0; gbuf[m1][b] = a1;
            __syncthreads();
            if (tid < 128) {
                int bb = tid & 31, dd = tid >> 5;
                float gi = gbuf[0 + dd][bb], gf = gbuf[4 + dd][bb];
                float gg = gbuf[8 + dd][bb], go = gbuf[12 + dd][bb];
                float c2 = sigf(gf) * clds[1][tid] + sigf(gi) * tanhf(gg);
                float h2 = sigf(go) * tanhf(c2);
                astore(&h1s[w * 16384 + bb * 512 + d0 + dd], c2);   // faithful bug
                H2[(size_t)(k - 1) * 16384 + bb * 512 + d0 + dd] = h2;
            }
        }

        if (k < 64) {                                   // ---- device barrier
            __threadfence();
            __syncthreads();
            if (tid == 0) {
                int old = __hip_atomic_fetch_add(&bar[0], 1, __ATOMIC_ACQ_REL,
                                                 __HIP_MEMORY_SCOPE_AGENT);
                if (old == NBLK - 1) {
                    __hip_atomic_store(&bar[0], 0, __ATOMIC_RELAXED, __HIP_MEMORY_SCOPE_AGENT);
                    __hip_atomic_store(&bar[1], k + 1, __ATOMIC_RELEASE, __HIP_MEMORY_SCOPE_AGENT);
                } else {
                    int spins = 0;
                    while (__hip_atomic_load(&bar[1], __ATOMIC_ACQUIRE,
                                             __HIP_MEMORY_SCOPE_AGENT) < k + 1) {
                        if (++spins > (1 << 20)) break;   // safety valve
                        __builtin_amdgcn_s_sleep(1);
                    }
                }
            }
            __syncthreads();
            __threadfence();
        }
    }
}

// ---------------------------------------------------------------------------
// XQ[t,b,:] = H2[t,b,:] @ W_in^T + b_in
// ---------------------------------------------------------------------------
__global__ void __launch_bounds__(256) k_x(const float* __restrict__ H2,
                                           const float* __restrict__ Win,
                                           const float* __restrict__ bin,
                                           float* __restrict__ XQ) {
    const int tid = threadIdx.x;
    const int j0 = blockIdx.x * 32;
    const int t = blockIdx.y;
    const int b = tid & 31, jj = tid >> 5;
    __shared__ float xs[32 * 257];
    float acc[4];
#pragma unroll
    for (int r = 0; r < 4; r++) acc[r] = bin[j0 + jj * 4 + r];
    const float* H2t = H2 + (size_t)t * 32 * 512;
    for (int c = 0; c < 2; c++) {
        for (int idx = tid; idx < 32 * 64; idx += 256) {
            int b2 = idx >> 6, k4 = idx & 63;
            f4 v = *(const f4*)&H2t[b2 * 512 + c * 256 + k4 * 4];
            float* dst = &xs[b2 * 257 + k4 * 4];
            dst[0] = v[0]; dst[1] = v[1]; dst[2] = v[2]; dst[3] = v[3];
        }
        __syncthreads();
        for (int k8 = 0; k8 < 32; k8++) {
            float w[4][8];
#pragma unroll
            for (int r = 0; r < 4; r++) {
                const f4* wp = (const f4*)&Win[(size_t)(j0 + jj * 4 + r) * 512 + c * 256 + k8 * 8];
                f4 wa = wp[0], wb = wp[1];
#pragma unroll
                for (int kk = 0; kk < 4; kk++) { w[r][kk] = wa[kk]; w[r][4 + kk] = wb[kk]; }
            }
#pragma unroll
            for (int kk = 0; kk < 8; kk++) {
                float xv = xs[b * 257 + k8 * 8 + kk];
#pragma unroll
                for (int r = 0; r < 4; r++) acc[r] += xv * w[r][kk];
            }
        }
        __syncthreads();
    }
    float* xrow = XQ + ((size_t)(t * 32 + b)) * 1024;
#pragma unroll
    for (int r = 0; r < 4; r++) xrow[j0 + jj * 4 + r] = acc[r];
}

// ---------------------------------------------------------------------------
// attention per (t,b): e = enc . xq, masked softmax, ctx = attn . enc
// ---------------------------------------------------------------------------
__global__ void __launch_bounds__(256) k_att(const float* __restrict__ XQ,
                                             const float* __restrict__ enc,
                                             const unsigned char* __restrict__ mask,
                                             const int* __restrict__ flag,
                                             float* __restrict__ CTX) {
    const int tid = threadIdx.x;
    const int b = blockIdx.x, t = blockIdx.y;
    __shared__ float xq[1024];
    __shared__ float ered[256];
    __shared__ float attn[128];
    __shared__ float red2[8];
    {
        f4 v = *(const f4*)&XQ[((size_t)(t * 32 + b)) * 1024 + tid * 4];
        float* dst = &xq[tid * 4];
        dst[0] = v[0]; dst[1] = v[1]; dst[2] = v[2]; dst[3] = v[3];
    }
    __syncthreads();
    const int s = tid >> 1, hh = tid & 1;
    float part = 0.f;
    const float* erow = enc + ((size_t)(b * 128 + s)) * 1024 + hh * 512;
    const float* xqh = &xq[hh * 512];
    for (int k4 = 0; k4 < 128; k4++) {
        f4 u = *(const f4*)&erow[k4 * 4];
#pragma unroll
        for (int kk = 0; kk < 4; kk++) part += u[kk] * xqh[k4 * 4 + kk];
    }
    ered[tid] = part;
    __syncthreads();
    float e = -INFINITY;
    if (tid < 128) {
        e = ered[2 * tid] + ered[2 * tid + 1];
        int f = *flag;
        bool msk;
        if (f == 0)      msk = mask[b * 128 + tid] != 0;
        else if (f == 1) msk = ((const int*)mask)[b * 128 + tid] != 0;
        else if (f == 2) msk = ((const u16*)mask)[b * 128 + tid] != 0;
        else             msk = ((const unsigned int*)mask)[b * 128 + tid] != 0;
        if (msk) e = -1e9f;
    }
    float v = e;
#pragma unroll
    for (int off = 32; off >= 1; off >>= 1) v = fmaxf(v, __shfl_xor(v, off));
    const int wave = tid >> 6;
    if ((tid & 63) == 0) red2[wave] = v;
    __syncthreads();
    float m = fmaxf(fmaxf(red2[0], red2[1]), fmaxf(red2[2], red2[3]));
    float p = (tid < 128) ? expf(e - m) : 0.f;
    float su = p;
#pragma unroll
    for (int off = 32; off >= 1; off >>= 1) su += __shfl_xor(su, off);
    __syncthreads();
    if ((tid & 63) == 0) red2[4 + wave] = su;
    __syncthreads();
    float S = (red2[4] + red2[5]) + (red2[6] + red2[7]);
    if (tid < 128) attn[tid] = p / S;
    __syncthreads();
    float c0 = 0, c1 = 0, c2 = 0, c3 = 0;
    const float* eb = enc + ((size_t)b * 128) * 1024 + tid * 4;
    for (int s2 = 0; s2 < 128; s2++) {
        float a = attn[s2];
        f4 u = *(const f4*)&eb[(size_t)s2 * 1024];
        c0 += a * u[0]; c1 += a * u[1]; c2 += a * u[2]; c3 += a * u[3];
    }
    float* crow = CTX + ((size_t)(t * 32 + b)) * 1024 + tid * 4;
    crow[0] = c0; crow[1] = c1; crow[2] = c2; crow[3] = c3;
}

// ---------------------------------------------------------------------------
// out[t,b,:] = tanh([ctx, s] @ W_out^T + b_out)  -> f32 d_out
// ---------------------------------------------------------------------------
__global__ void __launch_bounds__(256) k_out(const float* __restrict__ CTX,
                                             const float* __restrict__ H2,
                                             const float* __restrict__ Wout,
                                             const float* __restrict__ bout,
                                             float* __restrict__ out) {
    const int tid = threadIdx.x;
    const int j0 = blockIdx.x * 32;
    const int t = blockIdx.y;
    const int b = tid & 31, jj = tid >> 5;
    __shared__ float xs[32 * 257];
    float acc[4];
#pragma unroll
    for (int r = 0; r < 4; r++) acc[r] = bout[j0 + jj * 4 + r];
    const float* Ct = CTX + (size_t)t * 32 * 1024;
    const float* Ht = H2 + (size_t)t * 32 * 512;
    for (int c = 0; c < 6; c++) {
        for (int idx = tid; idx < 32 * 64; idx += 256) {
            int b2 = idx >> 6, k4 = idx & 63;
            const float* src = (c < 4) ? &Ct[b2 * 1024 + c * 256] : &Ht[b2 * 512 + (c - 4) * 256];
            f4 v = *(const f4*)&src[k4 * 4];
            float* dst = &xs[b2 * 257 + k4 * 4];
            dst[0] = v[0]; dst[1] = v[1]; dst[2] = v[2]; dst[3] = v[3];
        }
        __syncthreads();
        for (int k8 = 0; k8 < 32; k8++) {
            float w[4][8];
#pragma unroll
            for (int r = 0; r < 4; r++) {
                const f4* wp = (const f4*)&Wout[(size_t)(j0 + jj * 4 + r) * 1536 + c * 256 + k8 * 8];
                f4 wa = wp[0], wb = wp[1];
#pragma unroll
                for (int kk = 0; kk < 4; kk++) { w[r][kk] = wa[kk]; w[r][4 + kk] = wb[kk]; }
            }
#pragma unroll
            for (int kk = 0; kk < 8; kk++) {
                float xv = xs[b * 257 + k8 * 8 + kk];
#pragma unroll
                for (int r = 0; r < 4; r++) acc[r] += xv * w[r][kk];
            }
        }
        __syncthreads();
    }
    float* orow = out + ((size_t)(t * 32 + b)) * 512;
#pragma unroll
    for (int r = 0; r < 4; r++) orow[j0 + jj * 4 + r] = tanhf(acc[r]);
}

// ---------------------------------------------------------------------------
extern "C" void kernel_launch(void* const* d_in, const int* in_sizes, int n_in,
                              void* d_out, int out_size, void* d_ws, size_t ws_size,
                              hipStream_t stream) {
    const int* tokens   = (const int*)d_in[0];
    const float* enc    = (const float*)d_in[1];
    const float* hidden = (const float*)d_in[2];
    const float* cells  = (const float*)d_in[3];
    const unsigned char* mask = (const unsigned char*)d_in[4];
    const float* embed  = (const float*)d_in[5];
    const float* W_ih   = (const float*)d_in[6];
    const float* W_hh   = (const float*)d_in[7];
    const float* b_ih   = (const float*)d_in[8];
    const float* b_hh   = (const float*)d_in[9];
    const float* W_in   = (const float*)d_in[10];
    const float* b_in   = (const float*)d_in[11];
    const float* W_out  = (const float*)d_in[12];
    const float* b_out  = (const float*)d_in[13];
    float* out = (float*)d_out;

    float* ws = (float*)d_ws;
    float* gih0 = ws;                              // 4,194,304
    float* h0s  = ws + 4194304;                    // 32768 (2 parities)
    float* h20s = ws + 4227072;                    // 32768
    float* h1s  = ws + 4259840;                    // 32768
    float* H2   = ws + 4292608;                    // 1,048,576
    float* XQ   = ws + 5341184;                    // 2,097,152
    float* CTX  = ws + 7438336;                    // 2,097,152
    int*   flag = (int*)(ws + 9535488);
    int*   bar  = (int*)(ws + 9535492);

    const float* Whh0 = W_hh;
    const float* Wih1 = W_ih + (size_t)G4_ * DD;
    const float* Whh1 = W_hh + (size_t)G4_ * DD;
    const float* bih1 = b_ih + G4_;
    const float* bhh1 = b_hh + G4_;

    k_flag<<<1, 256, 0, stream>>>(mask, flag);
    k_init2<<<64, 256, 0, stream>>>(hidden, h0s, h1s, bar);
    k_gih0<<<dim3(64, 64), 256, 0, stream>>>(tokens, embed, W_ih, b_ih, b_hh, gih0);

    k_persist<<<NBLK, THR, 0, stream>>>(gih0, Whh0, Wih1, Whh1, bih1, bhh1, cells,
                                        h0s, h20s, h1s, H2, bar);

    k_x<<<dim3(32, 64), 256, 0, stream>>>(H2, W_in, b_in, XQ);
    k_att<<<dim3(32, 64), 256, 0, stream>>>(XQ, enc, mask, flag, CTX);
    k_out<<<dim3(16, 64), 256, 0, stream>>>(CTX, H2, W_out, b_out, out);
}

// Round 6
// 2216.079 us; speedup vs baseline: 12.8084x; 12.8084x over previous
//
#include <hip/hip_runtime.h>
#include <math.h>

typedef unsigned short u16;
typedef __attribute__((ext_vector_type(4))) float f4;

#define BB 32
#define TT 64
#define DD 512
#define G4_ 2048

__device__ __forceinline__ float sigf(float x) { return 1.0f / (1.0f + expf(-x)); }

// ---------------------------------------------------------------------------
// mask dtype classifier: 0=u8(bool), 1=i32, 2=bf16, 3=f32. Deterministic.
// ---------------------------------------------------------------------------
__global__ void k_flag(const unsigned char* __restrict__ m, int* __restrict__ flag) {
    int tid = threadIdx.x;
    int badbyte = 0, nonz_off = 0, evenu16_nz = 0;
    for (int i = tid * 16; i < tid * 16 + 16; i++) {
        unsigned char c = m[i];
        if (c > 1) badbyte = 1;
        if ((i & 3) != 0 && c != 0) nonz_off = 1;
    }
    const u16* mu = (const u16*)m;
    for (int i = tid * 8; i < tid * 8 + 8; i++) {
        if ((i & 1) == 0 && mu[i] != 0) evenu16_nz = 1;
    }
    __shared__ int s_bad, s_noff, s_env;
    if (tid == 0) { s_bad = 0; s_noff = 0; s_env = 0; }
    __syncthreads();
    if (badbyte) atomicOr(&s_bad, 1);
    if (nonz_off) atomicOr(&s_noff, 1);
    if (evenu16_nz) atomicOr(&s_env, 1);
    __syncthreads();
    if (tid == 0) {
        int f;
        if (s_bad) f = s_env ? 2 : 3;
        else       f = s_noff ? 0 : 1;
        *flag = f;
    }
}

// ---------------------------------------------------------------------------
// init: copy initial h-states into both parity buffers.
// ---------------------------------------------------------------------------
__global__ void __launch_bounds__(256) k_init2(const float* __restrict__ hid,
                                               float* __restrict__ h0s,
                                               float* __restrict__ h1s) {
    int i = blockIdx.x * 256 + threadIdx.x;   // 0 .. 16383
    float v0 = hid[i], v1 = hid[16384 + i];
    h0s[i] = v0; h0s[16384 + i] = v0;
    h1s[i] = v1; h1s[16384 + i] = v1;
}

// ---------------------------------------------------------------------------
// gih0[t][b][j] = b_ih0[j] + b_hh0[j] + sum_k embed[tok[b,t],k] * W_ih0[j,k]
// ---------------------------------------------------------------------------
__global__ void __launch_bounds__(256) k_gih0(const int* __restrict__ tokens,
                                              const float* __restrict__ embed,
                                              const float* __restrict__ Wih,
                                              const float* __restrict__ bih,
                                              const float* __restrict__ bhh,
                                              float* __restrict__ gih0) {
    const int tid = threadIdx.x;
    const int d0 = blockIdx.x * 8;
    const int t = blockIdx.y;
    const int b = tid & 31, dd = tid >> 5;
    const int d = d0 + dd;
    __shared__ float xs[32 * 257];
    __shared__ int toks[32];
    if (tid < 32) toks[tid] = tokens[tid * TT + t];
    float acc[4];
#pragma unroll
    for (int g = 0; g < 4; g++) { int j = g * 512 + d; acc[g] = bih[j] + bhh[j]; }
    __syncthreads();
    for (int c = 0; c < 2; c++) {
        for (int idx = tid; idx < 32 * 64; idx += 256) {
            int b2 = idx >> 6, k4 = idx & 63;
            f4 v = *(const f4*)&embed[(size_t)toks[b2] * 512 + c * 256 + k4 * 4];
            float* dst = &xs[b2 * 257 + k4 * 4];
            dst[0] = v[0]; dst[1] = v[1]; dst[2] = v[2]; dst[3] = v[3];
        }
        __syncthreads();
        for (int k8 = 0; k8 < 32; k8++) {
            float w[4][8];
#pragma unroll
            for (int g = 0; g < 4; g++) {
                const f4* wp = (const f4*)&Wih[(size_t)(g * 512 + d) * 512 + c * 256 + k8 * 8];
                f4 wa = wp[0], wb = wp[1];
#pragma unroll
                for (int kk = 0; kk < 4; kk++) { w[g][kk] = wa[kk]; w[g][4 + kk] = wb[kk]; }
            }
#pragma unroll
            for (int kk = 0; kk < 8; kk++) {
                float xv = xs[b * 257 + k8 * 8 + kk];
#pragma unroll
                for (int g = 0; g < 4; g++) acc[g] += xv * w[g][kk];
            }
        }
        __syncthreads();
    }
    float* grow = gih0 + ((size_t)(t * 32 + b)) * 2048;
#pragma unroll
    for (int g = 0; g < 4; g++) grow[g * 512 + d] = acc[g];
}

// ---------------------------------------------------------------------------
// Fused phase kernel (launched 65x; stream order = the grid sync).
// blocks [0,256):  stepA(t=k)   (k<64): d-slice 2, gates from gih0 + h0@Whh0^T
// blocks [256,512): stepB(t=k-1)(k>=1): d-slice 2, gates = h20@Wih1^T + h1@Whh1^T
// Row m = g*2+dd (dd=d-d0), global gate row j = g*512 + d0 + dd.
// ---------------------------------------------------------------------------
__global__ void __launch_bounds__(256) k_phase(
    const int k,
    const float* __restrict__ gih0,
    const float* __restrict__ Whh0,
    const float* __restrict__ Wih1,
    const float* __restrict__ Whh1,
    const float* __restrict__ bih1,
    const float* __restrict__ bhh1,
    const float* __restrict__ cells,
    const float* __restrict__ h0r, float* __restrict__ h0w,
    const float* __restrict__ h20r, float* __restrict__ h20w,
    const float* __restrict__ h1r, float* __restrict__ h1w,
    float* __restrict__ H2)
{
    const int tid = threadIdx.x;
    const int b = tid & 31, u = tid >> 5;       // u = row m, 0..7
    __shared__ float xs[32][257];
    __shared__ float gbuf[8][33];

    if (blockIdx.x < 256) {                     // ======== stepA (t = k)
        if (k >= 64) return;
        const int d0 = blockIdx.x * 2;
        const int j = (u >> 1) * 512 + d0 + (u & 1);
        float a = gih0[(size_t)k * 65536 + b * 2048 + j];
        const float* WA = Whh0 + (size_t)j * 512;
        for (int c = 0; c < 2; c++) {
            __syncthreads();
            for (int i = tid; i < 2048; i += 256) {
                int b2 = i >> 6, k4 = i & 63;
                *(f4*)&xs[b2][k4 * 4] = *(const f4*)&h0r[b2 * 512 + c * 256 + k4 * 4];
            }
            __syncthreads();
            const float* wp = WA + c * 256;
            for (int k4 = 0; k4 < 64; k4++) {
                f4 x = *(const f4*)&xs[b][k4 * 4];
                f4 w = *(const f4*)&wp[k4 * 4];
                a += x[0] * w[0]; a += x[1] * w[1]; a += x[2] * w[2]; a += x[3] * w[3];
            }
        }
        gbuf[u][b] = a;
        __syncthreads();
        if (tid < 64) {
            int bb = tid & 31, dd = tid >> 5;   // dd 0..1
            float gi = gbuf[0 + dd][bb], gf = gbuf[2 + dd][bb];
            float gg = gbuf[4 + dd][bb], go = gbuf[6 + dd][bb];
            float cell = cells[bb * 512 + d0 + dd];
            float c2 = sigf(gf) * cell + sigf(gi) * tanhf(gg);
            float h2 = sigf(go) * tanhf(c2);
            h0w[bb * 512 + d0 + dd] = c2;       // faithful bug: carry = cell
            h20w[bb * 512 + d0 + dd] = h2;
        }
    } else {                                    // ======== stepB (t = k-1)
        if (k < 1) return;
        const int d0 = (blockIdx.x - 256) * 2;
        const int j = (u >> 1) * 512 + d0 + (u & 1);
        float a = bih1[j] + bhh1[j];
        const float* WI = Wih1 + (size_t)j * 512;
        const float* WH = Whh1 + (size_t)j * 512;
        for (int c = 0; c < 4; c++) {
            const float* srcb = (c < 2) ? h20r : h1r;
            const int off = (c & 1) * 256;
            const float* wp = ((c < 2) ? WI : WH) + off;
            __syncthreads();
            for (int i = tid; i < 2048; i += 256) {
                int b2 = i >> 6, k4 = i & 63;
                *(f4*)&xs[b2][k4 * 4] = *(const f4*)&srcb[b2 * 512 + off + k4 * 4];
            }
            __syncthreads();
            for (int k4 = 0; k4 < 64; k4++) {
                f4 x = *(const f4*)&xs[b][k4 * 4];
                f4 w = *(const f4*)&wp[k4 * 4];
                a += x[0] * w[0]; a += x[1] * w[1]; a += x[2] * w[2]; a += x[3] * w[3];
            }
        }
        gbuf[u][b] = a;
        __syncthreads();
        if (tid < 64) {
            int bb = tid & 31, dd = tid >> 5;   // dd 0..1
            float gi = gbuf[0 + dd][bb], gf = gbuf[2 + dd][bb];
            float gg = gbuf[4 + dd][bb], go = gbuf[6 + dd][bb];
            float cell = cells[16384 + bb * 512 + d0 + dd];
            float c2 = sigf(gf) * cell + sigf(gi) * tanhf(gg);
            float h2 = sigf(go) * tanhf(c2);
            h1w[bb * 512 + d0 + dd] = c2;       // faithful bug
            H2[(size_t)(k - 1) * 16384 + bb * 512 + d0 + dd] = h2;
        }
    }
}

// ---------------------------------------------------------------------------
// XQ[t,b,:] = H2[t,b,:] @ W_in^T + b_in
// ---------------------------------------------------------------------------
__global__ void __launch_bounds__(256) k_x(const float* __restrict__ H2,
                                           const float* __restrict__ Win,
                                           const float* __restrict__ bin,
                                           float* __restrict__ XQ) {
    const int tid = threadIdx.x;
    const int j0 = blockIdx.x * 32;
    const int t = blockIdx.y;
    const int b = tid & 31, jj = tid >> 5;
    __shared__ float xs[32 * 257];
    float acc[4];
#pragma unroll
    for (int r = 0; r < 4; r++) acc[r] = bin[j0 + jj * 4 + r];
    const float* H2t = H2 + (size_t)t * 32 * 512;
    for (int c = 0; c < 2; c++) {
        for (int idx = tid; idx < 32 * 64; idx += 256) {
            int b2 = idx >> 6, k4 = idx & 63;
            f4 v = *(const f4*)&H2t[b2 * 512 + c * 256 + k4 * 4];
            float* dst = &xs[b2 * 257 + k4 * 4];
            dst[0] = v[0]; dst[1] = v[1]; dst[2] = v[2]; dst[3] = v[3];
        }
        __syncthreads();
        for (int k8 = 0; k8 < 32; k8++) {
            float w[4][8];
#pragma unroll
            for (int r = 0; r < 4; r++) {
                const f4* wp = (const f4*)&Win[(size_t)(j0 + jj * 4 + r) * 512 + c * 256 + k8 * 8];
                f4 wa = wp[0], wb = wp[1];
#pragma unroll
                for (int kk = 0; kk < 4; kk++) { w[r][kk] = wa[kk]; w[r][4 + kk] = wb[kk]; }
            }
#pragma unroll
            for (int kk = 0; kk < 8; kk++) {
                float xv = xs[b * 257 + k8 * 8 + kk];
#pragma unroll
                for (int r = 0; r < 4; r++) acc[r] += xv * w[r][kk];
            }
        }
        __syncthreads();
    }
    float* xrow = XQ + ((size_t)(t * 32 + b)) * 1024;
#pragma unroll
    for (int r = 0; r < 4; r++) xrow[j0 + jj * 4 + r] = acc[r];
}

// ---------------------------------------------------------------------------
// attention per (t,b): e = enc . xq, masked softmax, ctx = attn . enc
// ---------------------------------------------------------------------------
__global__ void __launch_bounds__(256) k_att(const float* __restrict__ XQ,
                                             const float* __restrict__ enc,
                                             const unsigned char* __restrict__ mask,
                                             const int* __restrict__ flag,
                                             float* __restrict__ CTX) {
    const int tid = threadIdx.x;
    const int b = blockIdx.x, t = blockIdx.y;
    __shared__ float xq[1024];
    __shared__ float ered[256];
    __shared__ float attn[128];
    __shared__ float red2[8];
    {
        f4 v = *(const f4*)&XQ[((size_t)(t * 32 + b)) * 1024 + tid * 4];
        float* dst = &xq[tid * 4];
        dst[0] = v[0]; dst[1] = v[1]; dst[2] = v[2]; dst[3] = v[3];
    }
    __syncthreads();
    const int s = tid >> 1, hh = tid & 1;
    float part = 0.f;
    const float* erow = enc + ((size_t)(b * 128 + s)) * 1024 + hh * 512;
    const float* xqh = &xq[hh * 512];
    for (int k4 = 0; k4 < 128; k4++) {
        f4 u = *(const f4*)&erow[k4 * 4];
#pragma unroll
        for (int kk = 0; kk < 4; kk++) part += u[kk] * xqh[k4 * 4 + kk];
    }
    ered[tid] = part;
    __syncthreads();
    float e = -INFINITY;
    if (tid < 128) {
        e = ered[2 * tid] + ered[2 * tid + 1];
        int f = *flag;
        bool msk;
        if (f == 0)      msk = mask[b * 128 + tid] != 0;
        else if (f == 1) msk = ((const int*)mask)[b * 128 + tid] != 0;
        else if (f == 2) msk = ((const u16*)mask)[b * 128 + tid] != 0;
        else             msk = ((const unsigned int*)mask)[b * 128 + tid] != 0;
        if (msk) e = -1e9f;
    }
    float v = e;
#pragma unroll
    for (int off = 32; off >= 1; off >>= 1) v = fmaxf(v, __shfl_xor(v, off));
    const int wave = tid >> 6;
    if ((tid & 63) == 0) red2[wave] = v;
    __syncthreads();
    float m = fmaxf(fmaxf(red2[0], red2[1]), fmaxf(red2[2], red2[3]));
    float p = (tid < 128) ? expf(e - m) : 0.f;
    float su = p;
#pragma unroll
    for (int off = 32; off >= 1; off >>= 1) su += __shfl_xor(su, off);
    __syncthreads();
    if ((tid & 63) == 0) red2[4 + wave] = su;
    __syncthreads();
    float S = (red2[4] + red2[5]) + (red2[6] + red2[7]);
    if (tid < 128) attn[tid] = p / S;
    __syncthreads();
    float c0 = 0, c1 = 0, c2 = 0, c3 = 0;
    const float* eb = enc + ((size_t)b * 128) * 1024 + tid * 4;
    for (int s2 = 0; s2 < 128; s2++) {
        float a = attn[s2];
        f4 u = *(const f4*)&eb[(size_t)s2 * 1024];
        c0 += a * u[0]; c1 += a * u[1]; c2 += a * u[2]; c3 += a * u[3];
    }
    float* crow = CTX + ((size_t)(t * 32 + b)) * 1024 + tid * 4;
    crow[0] = c0; crow[1] = c1; crow[2] = c2; crow[3] = c3;
}

// ---------------------------------------------------------------------------
// out[t,b,:] = tanh([ctx, s] @ W_out^T + b_out)  -> f32 d_out
// ---------------------------------------------------------------------------
__global__ void __launch_bounds__(256) k_out(const float* __restrict__ CTX,
                                             const float* __restrict__ H2,
                                             const float* __restrict__ Wout,
                                             const float* __restrict__ bout,
                                             float* __restrict__ out) {
    const int tid = threadIdx.x;
    const int j0 = blockIdx.x * 32;
    const int t = blockIdx.y;
    const int b = tid & 31, jj = tid >> 5;
    __shared__ float xs[32 * 257];
    float acc[4];
#pragma unroll
    for (int r = 0; r < 4; r++) acc[r] = bout[j0 + jj * 4 + r];
    const float* Ct = CTX + (size_t)t * 32 * 1024;
    const float* Ht = H2 + (size_t)t * 32 * 512;
    for (int c = 0; c < 6; c++) {
        for (int idx = tid; idx < 32 * 64; idx += 256) {
            int b2 = idx >> 6, k4 = idx & 63;
            const float* src = (c < 4) ? &Ct[b2 * 1024 + c * 256] : &Ht[b2 * 512 + (c - 4) * 256];
            f4 v = *(const f4*)&src[k4 * 4];
            float* dst = &xs[b2 * 257 + k4 * 4];
            dst[0] = v[0]; dst[1] = v[1]; dst[2] = v[2]; dst[3] = v[3];
        }
        __syncthreads();
        for (int k8 = 0; k8 < 32; k8++) {
            float w[4][8];
#pragma unroll
            for (int r = 0; r < 4; r++) {
                const f4* wp = (const f4*)&Wout[(size_t)(j0 + jj * 4 + r) * 1536 + c * 256 + k8 * 8];
                f4 wa = wp[0], wb = wp[1];
#pragma unroll
                for (int kk = 0; kk < 4; kk++) { w[r][kk] = wa[kk]; w[r][4 + kk] = wb[kk]; }
            }
#pragma unroll
            for (int kk = 0; kk < 8; kk++) {
                float xv = xs[b * 257 + k8 * 8 + kk];
#pragma unroll
                for (int r = 0; r < 4; r++) acc[r] += xv * w[r][kk];
            }
        }
        __syncthreads();
    }
    float* orow = out + ((size_t)(t * 32 + b)) * 512;
#pragma unroll
    for (int r = 0; r < 4; r++) orow[j0 + jj * 4 + r] = tanhf(acc[r]);
}

// ---------------------------------------------------------------------------
extern "C" void kernel_launch(void* const* d_in, const int* in_sizes, int n_in,
                              void* d_out, int out_size, void* d_ws, size_t ws_size,
                              hipStream_t stream) {
    const int* tokens   = (const int*)d_in[0];
    const float* enc    = (const float*)d_in[1];
    const float* hidden = (const float*)d_in[2];
    const float* cells  = (const float*)d_in[3];
    const unsigned char* mask = (const unsigned char*)d_in[4];
    const float* embed  = (const float*)d_in[5];
    const float* W_ih   = (const float*)d_in[6];
    const float* W_hh   = (const float*)d_in[7];
    const float* b_ih   = (const float*)d_in[8];
    const float* b_hh   = (const float*)d_in[9];
    const float* W_in   = (const float*)d_in[10];
    const float* b_in   = (const float*)d_in[11];
    const float* W_out  = (const float*)d_in[12];
    const float* b_out  = (const float*)d_in[13];
    float* out = (float*)d_out;

    float* ws = (float*)d_ws;
    float* gih0 = ws;                              // 4,194,304
    float* h0s  = ws + 4194304;                    // 32768 (2 parities)
    float* h20s = ws + 4227072;                    // 32768
    float* h1s  = ws + 4259840;                    // 32768
    float* H2   = ws + 4292608;                    // 1,048,576
    float* XQ   = ws + 5341184;                    // 2,097,152
    float* CTX  = ws + 7438336;                    // 2,097,152
    int*   flag = (int*)(ws + 9535488);

    const float* Whh0 = W_hh;
    const float* Wih1 = W_ih + (size_t)G4_ * DD;
    const float* Whh1 = W_hh + (size_t)G4_ * DD;
    const float* bih1 = b_ih + G4_;
    const float* bhh1 = b_hh + G4_;

    k_flag<<<1, 256, 0, stream>>>(mask, flag);
    k_init2<<<64, 256, 0, stream>>>(hidden, h0s, h1s);
    k_gih0<<<dim3(64, 64), 256, 0, stream>>>(tokens, embed, W_ih, b_ih, b_hh, gih0);

    for (int k = 0; k <= 64; k++) {
        const int r = k & 1, w = r ^ 1;
        k_phase<<<512, 256, 0, stream>>>(k, gih0, Whh0, Wih1, Whh1, bih1, bhh1, cells,
                                         h0s + r * 16384, h0s + w * 16384,
                                         h20s + r * 16384, h20s + w * 16384,
                                         h1s + r * 16384, h1s + w * 16384, H2);
    }

    k_x<<<dim3(32, 64), 256, 0, stream>>>(H2, W_in, b_in, XQ);
    k_att<<<dim3(32, 64), 256, 0, stream>>>(XQ, enc, mask, flag, CTX);
    k_out<<<dim3(16, 64), 256, 0, stream>>>(CTX, H2, W_out, b_out, out);
}